// Round 1
// baseline (267.758 us; speedup 1.0000x reference)
//
#include <hip/hip_runtime.h>

// Haar DWT: lfc[p] = s*(x[2p]+x[2p+1]); hfc[p] = s*(x[2p+1]-x[2p]), s=1/sqrt(2).
// Flat pair index p maps 1:1 to flat lfc/hfc index (rows of 8192 -> rows of 4096).
// Memory-bound: 64 MiB in + 64 MiB out. Each thread: 2x float4 load, 2x float4 store.

#define SQRT2_INV 0.70710678118654752440f

__global__ __launch_bounds__(256) void dwt_haar_kernel(
    const float4* __restrict__ x4,
    float4* __restrict__ lfc4,
    float4* __restrict__ hfc4,
    int n4)  // number of float4 outputs per branch
{
    int t = blockIdx.x * blockDim.x + threadIdx.x;
    if (t >= n4) return;

    float4 a = x4[2 * t];      // x[8t .. 8t+3]
    float4 b = x4[2 * t + 1];  // x[8t+4 .. 8t+7]

    float4 lo, hi;
    lo.x = SQRT2_INV * (a.x + a.y);
    lo.y = SQRT2_INV * (a.z + a.w);
    lo.z = SQRT2_INV * (b.x + b.y);
    lo.w = SQRT2_INV * (b.z + b.w);

    hi.x = SQRT2_INV * (a.y - a.x);
    hi.y = SQRT2_INV * (a.w - a.z);
    hi.z = SQRT2_INV * (b.y - b.x);
    hi.w = SQRT2_INV * (b.w - b.z);

    lfc4[t] = lo;
    hfc4[t] = hi;
}

extern "C" void kernel_launch(void* const* d_in, const int* in_sizes, int n_in,
                              void* d_out, int out_size, void* d_ws, size_t ws_size,
                              hipStream_t stream)
{
    const float* x = (const float*)d_in[0];   // (32, 64, 8192) f32
    // d_in[1] = matrix_low, d_in[2] = matrix_high: fixed Haar structure, unused.

    float* out = (float*)d_out;               // [lfc | hfc], each out_size/2 floats
    const int n_in_elems = in_sizes[0];       // 16,777,216
    const int n_pairs    = n_in_elems / 2;    // 8,388,608 per branch
    const int n4         = n_pairs / 4;       // 2,097,152 float4 outputs per branch

    const float4* x4    = (const float4*)x;
    float4*       lfc4  = (float4*)out;
    float4*       hfc4  = (float4*)(out + n_pairs);

    const int block = 256;
    const int grid  = (n4 + block - 1) / block;  // 8192
    dwt_haar_kernel<<<grid, block, 0, stream>>>(x4, lfc4, hfc4, n4);
}

// Round 3
// 264.179 us; speedup vs baseline: 1.0135x; 1.0135x over previous
//
#include <hip/hip_runtime.h>

// Haar DWT butterfly: lfc[p] = s*(x[2p]+x[2p+1]); hfc[p] = s*(x[2p+1]-x[2p]).
// Pairs never cross a float4 boundary, so each input float4 yields one lo
// float2 and one hi float2. Every global access is a fully lane-coalesced
// 16B op:
//   load  : thread t loads in4[base+t] and in4[base+256+t]   (coalesced x4)
//   repack: float2 results staged in LDS (8 KiB; 2-way bank alias = free)
//   store : read back as float4, coalesced 16B stores to lfc/hfc
// Nontemporal hints: pure streaming, no reuse.
// NOTE: use clang native vector type — __builtin_nontemporal_* rejects
// HIP_vector_type classes.

typedef float f4 __attribute__((ext_vector_type(4)));
typedef float f2 __attribute__((ext_vector_type(2)));

#define SQRT2_INV 0.70710678118654752440f

__global__ __launch_bounds__(256) void dwt_haar_lds(
    const f4* __restrict__ in4,
    f4* __restrict__ lo4,
    f4* __restrict__ hi4)
{
    __shared__ f2 slo[512];
    __shared__ f2 shi[512];

    const int tid = threadIdx.x;
    const long long ibase = (long long)blockIdx.x * 512;

    f4 a = __builtin_nontemporal_load(&in4[ibase + tid]);
    f4 b = __builtin_nontemporal_load(&in4[ibase + 256 + tid]);

    // input float4 j -> output float2 j (for both branches)
    slo[tid]       = (f2){SQRT2_INV * (a.x + a.y), SQRT2_INV * (a.z + a.w)};
    shi[tid]       = (f2){SQRT2_INV * (a.y - a.x), SQRT2_INV * (a.w - a.z)};
    slo[tid + 256] = (f2){SQRT2_INV * (b.x + b.y), SQRT2_INV * (b.z + b.w)};
    shi[tid + 256] = (f2){SQRT2_INV * (b.y - b.x), SQRT2_INV * (b.w - b.z)};

    __syncthreads();

    const f4* slo4 = (const f4*)slo;
    const f4* shi4 = (const f4*)shi;
    const long long obase = (long long)blockIdx.x * 256;

    __builtin_nontemporal_store(slo4[tid], &lo4[obase + tid]);
    __builtin_nontemporal_store(shi4[tid], &hi4[obase + tid]);
}

extern "C" void kernel_launch(void* const* d_in, const int* in_sizes, int n_in,
                              void* d_out, int out_size, void* d_ws, size_t ws_size,
                              hipStream_t stream)
{
    const float* x = (const float*)d_in[0];   // (32, 64, 8192) f32
    // d_in[1], d_in[2]: fixed Haar band matrices — structure known, unused.

    float* out = (float*)d_out;               // [lfc | hfc] concatenated flat
    const int n_in_elems = in_sizes[0];       // 16,777,216 floats
    const int n_pairs    = n_in_elems / 2;    // 8,388,608 per branch
    const int n_in4      = n_in_elems / 4;    // 4,194,304 input float4s

    const f4* in4 = (const f4*)x;
    f4*       lo4 = (f4*)out;
    f4*       hi4 = (f4*)(out + n_pairs);

    const int block = 256;
    const int grid  = n_in4 / (2 * block);    // 8192 blocks, exact coverage
    dwt_haar_lds<<<grid, block, 0, stream>>>(in4, lo4, hi4);
}